// Round 5
// baseline (9561.578 us; speedup 1.0000x reference)
//
#include <hip/hip_runtime.h>
#include <stdint.h>

#define H 128
#define G 512   // 4*H
#define T 2048
#define B 256
#define NF 5

#define KLO 56            // W_ih1 columns staged in LDS (28 float2 pairs)
#define KHI (H - KLO)     // 72 columns in VGPRs

__device__ __forceinline__ float sigmoidf_(float x) {
  return 1.0f / (1.0f + __expf(-x));
}
__device__ __forceinline__ float tanhf_(float x) {
  float e = __expf(2.0f * x);
  return 1.0f - 2.0f / (e + 1.0f);
}

// zero the persistent state block (4*B*H floats: h0,c0,h1s,c1s)
__global__ void init_state(float* __restrict__ st) {
  int i = blockIdx.x * blockDim.x + threadIdx.x;
  if (i < 4 * B * H) st[i] = 0.0f;
}

// ---- Layer 0 chunk: steps [s0, s0+CH), writes h1buf[B][CH][H] ----
__global__ __launch_bounds__(512, 2)
void lstm0(const float* __restrict__ x, const float* __restrict__ Wih,
           const float* __restrict__ Whh, const float* __restrict__ bih,
           const float* __restrict__ bhh, float* __restrict__ h0st,
           float* __restrict__ c0st, float* __restrict__ h1buf,
           int s0, int CH)
{
  const int b = blockIdx.x;
  const int t = threadIdx.x;      // gate row 0..511
  __shared__ float4 h4[H/4];
  __shared__ float gates[G];
  float* hs = (float*)h4;

  float4 w[H/4];
  #pragma unroll
  for (int i = 0; i < H/4; ++i) w[i] = ((const float4*)Whh)[t*(H/4) + i];
  const float wi0 = Wih[t*NF+0], wi1 = Wih[t*NF+1], wi2 = Wih[t*NF+2],
              wi3 = Wih[t*NF+3], wi4 = Wih[t*NF+4];
  const float bias = bih[t] + bhh[t];
  float c = 0.0f;
  if (t < H) { hs[t] = h0st[b*H + t]; c = c0st[b*H + t]; }
  __syncthreads();

  const float* xb  = x + ((size_t)b * T + s0) * NF;
  float*       h1b = h1buf + (size_t)b * CH * H;
  for (int s = 0; s < CH; ++s) {
    // input projection: x_t is wave-uniform -> scalar-cache loads
    float a0 = bias + wi0*xb[s*NF+0] + wi1*xb[s*NF+1] + wi2*xb[s*NF+2]
                    + wi3*xb[s*NF+3] + wi4*xb[s*NF+4];
    float a1 = 0.f, a2 = 0.f, a3 = 0.f;
    #pragma unroll
    for (int i = 0; i < H/4; ++i) {
      float4 hv = h4[i];             // broadcast ds_read_b128
      a0 += w[i].x * hv.x;
      a1 += w[i].y * hv.y;
      a2 += w[i].z * hv.z;
      a3 += w[i].w * hv.w;
    }
    gates[t] = (a0 + a1) + (a2 + a3);
    __syncthreads();
    if (t < H) {
      float gi = sigmoidf_(gates[t]);
      float gf = sigmoidf_(gates[H + t]);
      float gg = tanhf_  (gates[2*H + t]);
      float go = sigmoidf_(gates[3*H + t]);
      c = gf * c + gi * gg;
      float h = go * tanhf_(c);
      hs[t] = h;
      h1b[(size_t)s*H + t] = h;      // coalesced 512B store
    }
    __syncthreads();
  }
  if (t < H) { h0st[b*H + t] = hs[t]; c0st[b*H + t] = c; }
}

// ---- Layer 1 chunk: consumes h1buf, updates state, writes h2last at t=T-1 ----
__global__ __launch_bounds__(512, 2)
void lstm1(const float* __restrict__ h1buf, const float* __restrict__ Wih,
           const float* __restrict__ Whh, const float* __restrict__ bih,
           const float* __restrict__ bhh, float* __restrict__ h1st,
           float* __restrict__ c1st, float* __restrict__ h2last,
           int s0, int CH)
{
  const int b = blockIdx.x;
  const int t = threadIdx.x;
  __shared__ float2 Wlo[KLO/2][G];   // 114688 B, column-major: 2-way bank alias (free)
  __shared__ float4 h4[H/4];
  __shared__ float gates[G];
  __shared__ float4 xb4[2][H/4];     // double-buffered h1_t
  float* hs = (float*)h4;

  #pragma unroll
  for (int i = 0; i < KLO/2; ++i)
    Wlo[i][t] = make_float2(Wih[t*H + 2*i], Wih[t*H + 2*i + 1]);
  float4 wh[KHI/4];
  #pragma unroll
  for (int i = 0; i < KHI/4; ++i) wh[i] = ((const float4*)(Wih + t*H + KLO))[i];
  float4 w[H/4];
  #pragma unroll
  for (int i = 0; i < H/4; ++i) w[i] = ((const float4*)Whh)[t*(H/4) + i];
  const float bias = bih[t] + bhh[t];
  float c = 0.0f;
  if (t < H) { hs[t] = h1st[b*H + t]; c = c1st[b*H + t]; }

  const float4* h1b = (const float4*)(h1buf + (size_t)b * CH * H);
  if (t >= 128 && t < 128 + H/4) xb4[0][t - 128] = h1b[t - 128];  // prefetch step 0
  __syncthreads();

  for (int s = 0; s < CH; ++s) {
    const int cur = s & 1;
    const float* xs = (const float*)xb4[cur];
    float a0 = bias, a1 = 0.f, a2 = 0.f, a3 = 0.f;
    #pragma unroll
    for (int i = 0; i < KLO/2; ++i) {
      float2 wv = Wlo[i][t];
      a0 += wv.x * xs[2*i];
      a1 += wv.y * xs[2*i + 1];
    }
    #pragma unroll
    for (int i = 0; i < KHI/4; ++i) {
      float4 xv = ((const float4*)(xs + KLO))[i];  // broadcast
      a0 += wh[i].x * xv.x; a1 += wh[i].y * xv.y;
      a2 += wh[i].z * xv.z; a3 += wh[i].w * xv.w;
    }
    #pragma unroll
    for (int i = 0; i < H/4; ++i) {
      float4 hv = h4[i];                           // broadcast
      a0 += w[i].x * hv.x; a1 += w[i].y * hv.y;
      a2 += w[i].z * hv.z; a3 += w[i].w * hv.w;
    }
    gates[t] = (a0 + a1) + (a2 + a3);
    __syncthreads();
    if (t < H) {
      float gi = sigmoidf_(gates[t]);
      float gf = sigmoidf_(gates[H + t]);
      float gg = tanhf_  (gates[2*H + t]);
      float go = sigmoidf_(gates[3*H + t]);
      c = gf * c + gi * gg;
      float h = go * tanhf_(c);
      hs[t] = h;
      if (s0 + s == T - 1) h2last[(size_t)b*H + t] = h;
    } else if (t >= 128 && t < 160 && s + 1 < CH) {
      xb4[cur ^ 1][t - 128] = h1b[(size_t)(s + 1)*(H/4) + (t - 128)];
    }
    __syncthreads();
  }
  if (t < H) { h1st[b*H + t] = hs[t]; c1st[b*H + t] = c; }
}

// ---- Output: JAX partitionable-threefry dropout mask + 7x128 GEMV ----
__device__ __forceinline__ void threefry2x32_(uint32_t x0, uint32_t x1,
                                              uint32_t* o0, uint32_t* o1)
{
  const uint32_t k0 = 0u, k1 = 42u;
  const uint32_t k2 = k0 ^ k1 ^ 0x1BD11BDAu;
  x0 += k0; x1 += k1;
#define RR_(x, r) (((x) << (r)) | ((x) >> (32 - (r))))
#define RND_(r) { x0 += x1; x1 = RR_(x1, r); x1 ^= x0; }
  RND_(13) RND_(15) RND_(26) RND_(6)   x0 += k1; x1 += k2 + 1u;
  RND_(17) RND_(29) RND_(16) RND_(24)  x0 += k2; x1 += k0 + 2u;
  RND_(13) RND_(15) RND_(26) RND_(6)   x0 += k0; x1 += k1 + 3u;
  RND_(17) RND_(29) RND_(16) RND_(24)  x0 += k1; x1 += k2 + 4u;
  RND_(13) RND_(15) RND_(26) RND_(6)   x0 += k2; x1 += k0 + 5u;
#undef RND_
#undef RR_
  *o0 = x0; *o1 = x1;
}

__global__ void out_kernel(const float* __restrict__ h2last,
                           const float* __restrict__ Wout,
                           const float* __restrict__ bout,
                           float* __restrict__ out)
{
  const int b = blockIdx.x;
  const int j = threadIdx.x;   // 0..127
  __shared__ float vals[H];
  uint32_t m = (uint32_t)(b * H + j);
  // jax_threefry_partitionable=True (default since JAX 0.4.36):
  //   counts1, counts2 = iota_2x32_shape(shape)   -> (hi, lo) = (0, m)
  //   bits1, bits2 = threefry2x32(key, (0, m))
  //   bit_width 32: bits = bits1 ^ bits2
  uint32_t o0, o1;
  threefry2x32_(0u, m, &o0, &o1);
  uint32_t bits = o0 ^ o1;
  float u = __uint_as_float(0x3f800000u | (bits >> 9)) - 1.0f;  // uniform [0,1)
  float v = (u < 0.7f) ? (h2last[m] / 0.7f) : 0.0f;
  vals[j] = v;
  __syncthreads();
  if (j < 7) {
    float a = bout[j];
    #pragma unroll
    for (int k = 0; k < H; ++k) a += vals[k] * Wout[j*H + k];
    out[b*7 + j] = a;
  }
}

extern "C" void kernel_launch(void* const* d_in, const int* in_sizes, int n_in,
                              void* d_out, int out_size, void* d_ws, size_t ws_size,
                              hipStream_t stream) {
  const float* x    = (const float*)d_in[0];
  const float* Wih0 = (const float*)d_in[1];
  const float* Whh0 = (const float*)d_in[2];
  const float* bih0 = (const float*)d_in[3];
  const float* bhh0 = (const float*)d_in[4];
  const float* Wih1 = (const float*)d_in[5];
  const float* Whh1 = (const float*)d_in[6];
  const float* bih1 = (const float*)d_in[7];
  const float* bhh1 = (const float*)d_in[8];
  const float* Wout = (const float*)d_in[9];
  const float* bout = (const float*)d_in[10];

  // ws layout: [h0 | c0 | h1s | c1s | h2last] (5*B*H f32 = 640 KB) then h1buf
  float* st   = (float*)d_ws;
  float* h0s  = st;
  float* c0s  = st + 1*B*H;
  float* h1s  = st + 2*B*H;
  float* c1s  = st + 3*B*H;
  float* h2l  = st + 4*B*H;
  float* h1buf = st + 5*B*H;
  float* out  = (float*)d_out;

  const size_t state_bytes = (size_t)5 * B * H * sizeof(float);
  const size_t per_step    = (size_t)B * H * sizeof(float);   // 128 KB / time step
  int CH = 1;
  if (ws_size > state_bytes) {
    size_t m = (ws_size - state_bytes) / per_step;
    while (CH * 2 <= (int)m && CH * 2 <= T) CH *= 2;          // pow2 divisor of T
  }

  init_state<<<(4*B*H + 255)/256, 256, 0, stream>>>(st);
  for (int s0 = 0; s0 < T; s0 += CH) {
    lstm0<<<B, 512, 0, stream>>>(x, Wih0, Whh0, bih0, bhh0, h0s, c0s, h1buf, s0, CH);
    lstm1<<<B, 512, 0, stream>>>(h1buf, Wih1, Whh1, bih1, bhh1, h1s, c1s, h2l, s0, CH);
  }
  out_kernel<<<B, H, 0, stream>>>(h2l, Wout, bout, out);
}